// Round 2
// baseline (640.832 us; speedup 1.0000x reference)
//
#include <hip/hip_runtime.h>

#define BB 16
#define HH 512
#define NH 32          // complex modes per h
#define LL 4096
#define TCH 64         // chunk length
#define NCH 64         // LL/TCH chunks per sequence
#define KA 128         // A-panel K: 64 u-taps + 64 state components

static_assert(TCH * NCH == LL, "chunking");

typedef __attribute__((ext_vector_type(8))) short bf16x8;
typedef __attribute__((ext_vector_type(4))) float f32x4;

// RNE float->bf16 bits
static __device__ __forceinline__ unsigned short f2bf(float x) {
    unsigned int u = __builtin_bit_cast(unsigned int, x);
    u = (u + 0x7fffu + ((u >> 16) & 1u)) >> 16;
    return (unsigned short)u;
}
static __device__ __forceinline__ float bf2f(unsigned short b) {
    return __builtin_bit_cast(float, ((unsigned)b) << 16);
}
static __device__ __forceinline__ unsigned pack2(float a, float b) {
    return (unsigned)f2bf(a) | ((unsigned)f2bf(b) << 16);
}

static __device__ __forceinline__ void gload_lds16(const void* g, void* l) {
#if __has_builtin(__builtin_amdgcn_global_load_lds)
    __builtin_amdgcn_global_load_lds(
        (const __attribute__((address_space(1))) unsigned int*)g,
        (__attribute__((address_space(3))) unsigned int*)l, 16, 0, 0);
#else
    *(uint4*)l = *(const uint4*)g;
#endif
}

// ---------------- k0: SSM scalar parameters ----------------
__global__ void k0_params(const float* __restrict__ C,
                          const float* __restrict__ log_dt,
                          const float* __restrict__ lAr,
                          const float* __restrict__ Aim,
                          float* __restrict__ c2R,  float* __restrict__ c2I,
                          float* __restrict__ ltR,  float* __restrict__ ltI,
                          float* __restrict__ xrA,  float* __restrict__ xiA)
{
    int tid = blockIdx.x * 256 + threadIdx.x;
    if (tid >= HH * NH) return;
    int h = tid >> 5;
    float dt = expf(log_dt[h]);
    float Ar = -expf(lAr[tid]);
    float Ai = Aim[tid];
    float xr = Ar * dt, xi = Ai * dt;      // log Lambda
    xrA[tid] = xr; xiA[tid] = xi;
    float er = expf(xr);
    float lr = er * cosf(xi);
    float li = er * sinf(xi);
    float wr = lr - 1.0f, wi = li;
    float inv = 1.0f / (Ar * Ar + Ai * Ai);
    float qr = (wr * Ar + wi * Ai) * inv;   // (Lam-1)/A
    float qi = (wi * Ar - wr * Ai) * inv;
    float cr = C[2 * tid], ci = C[2 * tid + 1];
    c2R[tid] =  2.0f * (cr * qr - ci * qi); // y = c2R*Re(s) + c2I*Im(s)
    c2I[tid] = -2.0f * (cr * qi + ci * qr);
    float eT = expf((float)TCH * xr);       // Lambda^TCH
    float aT = (float)TCH * xi;
    ltR[tid] = eT * cosf(aT);
    ltI[tid] = eT * sinf(aT);
}

// ---------------- kw: pack W (row-permuted for GLU) + bias ----------------
__global__ void kw_pack(const float* __restrict__ W, const float* __restrict__ bias,
                        unsigned short* __restrict__ Wp, float* __restrict__ bp)
{
    int tid = blockIdx.x * 256 + threadIdx.x;      // 65536
    int drow = tid >> 6;
    int kc = (tid & 63) * 8;
    int src = (drow & 1) ? (drow >> 1) + HH : (drow >> 1);
    const float4* s = (const float4*)(W + (size_t)src * HH + kc);
    float4 a = s[0], b4 = s[1];
    uint4 pack;
    pack.x = pack2(a.x, a.y);
    pack.y = pack2(a.z, a.w);
    pack.z = pack2(b4.x, b4.y);
    pack.w = pack2(b4.z, b4.w);
    *(uint4*)(Wp + (size_t)drow * HH + kc) = pack;
    if (tid < 2 * HH)
        bp[tid] = bias[(tid & 1) ? (tid >> 1) + HH : (tid >> 1)];
}

// ---------------- kA: build per-h matrices M|G (Apan) and V (Vpan) ----------------
// Apan[h][t][0..63]   = M[t][tau] = k[t-tau] (t>=tau)          (intra-chunk conv)
// Apan[h][t][64+2n+c] = G: y_state[t] = sum_j G[t][j]*S[j]
// Vpan[h][j][tau]     : E[j] = sum_tau V[j][tau]*u[tau],  j=2n(+1) = Re/Im comp
__global__ __launch_bounds__(64) void kA_build(
    const float* __restrict__ c2R, const float* __restrict__ c2I,
    const float* __restrict__ xrA, const float* __restrict__ xiA,
    unsigned short* __restrict__ Apan, unsigned short* __restrict__ Vpan)
{
    int h = blockIdx.x;
    int t = threadIdx.x;                  // 0..63
    __shared__ float s_xr[NH], s_xi[NH], s_cr[NH], s_ci[NH], s_k[TCH];
    if (t < NH) {
        s_xr[t] = xrA[h * NH + t]; s_xi[t] = xiA[h * NH + t];
        s_cr[t] = c2R[h * NH + t]; s_ci[t] = c2I[h * NH + t];
    }
    __syncthreads();
    // k[d], d = t:  k[d] = sum_n c2R*Re(Lam^d) + c2I*Im(Lam^d)
    {
        float d = (float)t;
        float acc = 0.f;
#pragma unroll
        for (int n = 0; n < NH; ++n) {
            float er = __expf(s_xr[n] * d);
            float sv, cv; __sincosf(s_xi[n] * d, &sv, &cv);
            acc = fmaf(s_cr[n], er * cv, fmaf(s_ci[n], er * sv, acc));
        }
        s_k[t] = acc;
    }
    __syncthreads();
    // row t of Apan[h]
    unsigned short row[KA];
#pragma unroll
    for (int tau = 0; tau < TCH; ++tau)
        row[tau] = f2bf((tau <= t) ? s_k[t - tau] : 0.f);
    float tp = (float)(t + 1);
#pragma unroll
    for (int n = 0; n < NH; ++n) {
        float er = __expf(s_xr[n] * tp);
        float sv, cv; __sincosf(s_xi[n] * tp, &sv, &cv);
        float pr = er * cv, pi = er * sv;           // Lam^{t+1}
        row[TCH + 2 * n]     = f2bf(fmaf(s_cr[n], pr,  s_ci[n] * pi));
        row[TCH + 2 * n + 1] = f2bf(fmaf(s_ci[n], pr, -s_cr[n] * pi));
    }
    {
        uint4* dst = (uint4*)(Apan + ((size_t)h * TCH + t) * KA);
        const uint4* src = (const uint4*)row;
#pragma unroll
        for (int i = 0; i < 16; ++i) dst[i] = src[i];
    }
    // row t of Vpan[h]: n = t>>1, comp = t&1:  V[t][tau] = Re/Im(Lam^{63-tau})
    {
        int n = t >> 1, cm = t & 1;
        float xr = s_xr[n], xi = s_xi[n];
        unsigned short vrow[TCH];
#pragma unroll
        for (int tau = 0; tau < TCH; ++tau) {
            float p = (float)(TCH - 1 - tau);
            float er = __expf(xr * p);
            float sv, cv; __sincosf(xi * p, &sv, &cv);
            vrow[tau] = f2bf(cm ? er * sv : er * cv);
        }
        uint4* vd = (uint4*)(Vpan + ((size_t)h * TCH + t) * TCH);
        const uint4* vs = (const uint4*)vrow;
#pragma unroll
        for (int i = 0; i < 8; ++i) vd[i] = vs[i];
    }
}

// ---------------- kB: E = V @ U  (per h, per b) ----------------
// ES[((b*HH+h)*NCH + c)*TCH + j] = E_j of chunk c  (bf16)
__global__ __launch_bounds__(256, 2) void kB_estate(
    const float* __restrict__ u, const unsigned short* __restrict__ Vpan,
    unsigned short* __restrict__ ES)
{
    __shared__ unsigned short Vs[TCH * TCH];     // 8KB, row stride 128B, XOR-swizzled
    int h = blockIdx.x & (HH - 1), g = blockIdx.x >> 9;
    int tid = threadIdx.x;
    {
        int row = tid >> 2, part = tid & 3;      // 32B per thread
        const uint4* src = (const uint4*)(Vpan + ((size_t)h * TCH + row) * TCH + part * 16);
        uint4 a = src[0], b4 = src[1];
        char* rb = (char*)Vs + row * 128;
        int b0 = part * 32;
        *(uint4*)(rb + ((b0)      ^ ((row & 7) << 4))) = a;
        *(uint4*)(rb + ((b0 + 16) ^ ((row & 7) << 4))) = b4;
    }
    __syncthreads();
    int lane = tid & 63, w = tid >> 6;
    int b = g * 4 + w;
    int lrow = lane & 15, lk8 = (lane >> 4) * 8;
    f32x4 acc[4][4];
#pragma unroll
    for (int m = 0; m < 4; ++m)
#pragma unroll
        for (int n = 0; n < 4; ++n) { f32x4 z = {0.f,0.f,0.f,0.f}; acc[m][n] = z; }
    const float* ug = u + ((size_t)b * HH + h) * LL;
#pragma unroll
    for (int ks = 0; ks < 2; ++ks) {
        bf16x8 bfr[4];
#pragma unroll
        for (int n = 0; n < 4; ++n) {
            int c = n * 16 + lrow;
            const float* up = ug + c * TCH + ks * 32 + lk8;
            float4 f0 = *(const float4*)up, f1 = *(const float4*)(up + 4);
            bf16x8 v;
            v[0]=f2bf(f0.x); v[1]=f2bf(f0.y); v[2]=f2bf(f0.z); v[3]=f2bf(f0.w);
            v[4]=f2bf(f1.x); v[5]=f2bf(f1.y); v[6]=f2bf(f1.z); v[7]=f2bf(f1.w);
            bfr[n] = v;
        }
#pragma unroll
        for (int m = 0; m < 4; ++m) {
            int row = m * 16 + lrow;
            int bo = (ks * 32 + lk8) * 2;
            bf16x8 af = *(const bf16x8*)((char*)Vs + row * 128 + (bo ^ ((row & 7) << 4)));
#pragma unroll
            for (int n = 0; n < 4; ++n)
                acc[m][n] = __builtin_amdgcn_mfma_f32_16x16x32_bf16(af, bfr[n], acc[m][n], 0, 0, 0);
        }
    }
    unsigned short* Eb = ES + ((size_t)b * HH + h) * (NCH * TCH);
#pragma unroll
    for (int m = 0; m < 4; ++m) {
        int j0 = m * 16 + (lane >> 4) * 4;
#pragma unroll
        for (int n = 0; n < 4; ++n) {
            int c = n * 16 + lrow;
            f32x4 v = acc[m][n];
            uint2 p; p.x = pack2(v[0], v[1]); p.y = pack2(v[2], v[3]);
            *(uint2*)(Eb + (size_t)c * TCH + j0) = p;
        }
    }
}

// ---------------- kC: inter-chunk scan (in-place E -> entry states S) ----------------
__global__ void kC_scan(const float* __restrict__ ltR, const float* __restrict__ ltI,
                        unsigned short* __restrict__ ES)
{
    int tid = blockIdx.x * 256 + threadIdx.x;   // BB*HH*NH = 262144
    int n = tid & (NH - 1);
    int bh = tid >> 5;
    int h = bh & (HH - 1);
    float ar = ltR[h * NH + n], ai = ltI[h * NH + n];
    unsigned short* base = ES + (size_t)bh * (NCH * TCH) + 2 * n;
    float sr = 0.f, si = 0.f;
#pragma unroll 8
    for (int c = 0; c < NCH; ++c) {
        unsigned e = *(unsigned*)(base + (size_t)c * TCH);
        float er = bf2f((unsigned short)(e & 0xffff));
        float ei = bf2f((unsigned short)(e >> 16));
        *(unsigned*)(base + (size_t)c * TCH) = pack2(sr, si);
        float nsr = fmaf(ar, sr, fmaf(-ai, si, er));
        float nsi = fmaf(ar, si, fmaf(ai, sr, ei));
        sr = nsr; si = nsi;
    }
}

// ---------------- kD: Y = [M|G] @ [u_c; S_c]  + D*u + GELU -> yb bf16 [b*l][h] ----------------
__global__ __launch_bounds__(256, 2) void kD_y(
    const float* __restrict__ u, const unsigned short* __restrict__ Apan,
    const unsigned short* __restrict__ ES, const float* __restrict__ Dv,
    unsigned short* __restrict__ yb)
{
    __shared__ unsigned short As_[TCH * KA];     // 16KB, row stride 256B, XOR-swizzled
    int h = blockIdx.x & (HH - 1), g = blockIdx.x >> 9;
    int tid = threadIdx.x;
    {
        int row = tid >> 2, part = tid & 3;      // 64B per thread
        const uint4* src = (const uint4*)(Apan + ((size_t)h * TCH + row) * KA + part * 32);
        uint4 v0 = src[0], v1 = src[1], v2 = src[2], v3 = src[3];
        char* rb = (char*)As_ + row * 256;
        int b0 = part * 64, sw = (row & 7) << 4;
        *(uint4*)(rb + ((b0)      ^ sw)) = v0;
        *(uint4*)(rb + ((b0 + 16) ^ sw)) = v1;
        *(uint4*)(rb + ((b0 + 32) ^ sw)) = v2;
        *(uint4*)(rb + ((b0 + 48) ^ sw)) = v3;
    }
    __syncthreads();
    int lane = tid & 63, w = tid >> 6;
    int b = g * 4 + w;
    int lrow = lane & 15, lk8 = (lane >> 4) * 8;
    f32x4 acc[4][4];
#pragma unroll
    for (int m = 0; m < 4; ++m)
#pragma unroll
        for (int n = 0; n < 4; ++n) { f32x4 z = {0.f,0.f,0.f,0.f}; acc[m][n] = z; }
    const float* ug = u + ((size_t)b * HH + h) * LL;
    const unsigned short* Sg = ES + ((size_t)b * HH + h) * (NCH * TCH);
#pragma unroll
    for (int ks = 0; ks < 4; ++ks) {
        bf16x8 bfr[4];
#pragma unroll
        for (int n = 0; n < 4; ++n) {
            int c = n * 16 + lrow;
            if (ks < 2) {
                const float* up = ug + c * TCH + ks * 32 + lk8;
                float4 f0 = *(const float4*)up, f1 = *(const float4*)(up + 4);
                bf16x8 v;
                v[0]=f2bf(f0.x); v[1]=f2bf(f0.y); v[2]=f2bf(f0.z); v[3]=f2bf(f0.w);
                v[4]=f2bf(f1.x); v[5]=f2bf(f1.y); v[6]=f2bf(f1.z); v[7]=f2bf(f1.w);
                bfr[n] = v;
            } else {
                bfr[n] = *(const bf16x8*)(Sg + (size_t)c * TCH + (ks - 2) * 32 + lk8);
            }
        }
#pragma unroll
        for (int m = 0; m < 4; ++m) {
            int row = m * 16 + lrow;
            int bo = (ks * 32 + lk8) * 2;
            bf16x8 af = *(const bf16x8*)((char*)As_ + row * 256 + (bo ^ ((row & 7) << 4)));
#pragma unroll
            for (int n = 0; n < 4; ++n)
                acc[m][n] = __builtin_amdgcn_mfma_f32_16x16x32_bf16(af, bfr[n], acc[m][n], 0, 0, 0);
        }
    }
    // epilogue: + D*u (fp32, L1-hot re-read), GELU, scatter-store yb
    float Dh = Dv[h];
#pragma unroll
    for (int m = 0; m < 4; ++m) {
        int t0 = m * 16 + (lane >> 4) * 4;
#pragma unroll
        for (int n = 0; n < 4; ++n) {
            int c = n * 16 + lrow;
            float4 uv = *(const float4*)(ug + c * TCH + t0);
            f32x4 v = acc[m][n];
            unsigned short* yp = yb + ((size_t)b * LL + (size_t)c * TCH + t0) * HH + h;
            float uu[4] = {uv.x, uv.y, uv.z, uv.w};
#pragma unroll
            for (int r = 0; r < 4; ++r) {
                float yo = fmaf(Dh, uu[r], v[r]);
                float ge = 0.5f * yo * (1.0f + erff(yo * 0.70710678118f));
                yp[(size_t)r * HH] = f2bf(ge);
            }
        }
    }
}

// ---------------- k4: GEMM z = Wp*y + bp, fused GLU (unchanged, known-good) ----------------
#define BM 128
#define BN 128
#define BKK 32

__global__ __launch_bounds__(256, 2) void k4_gemm(
    const unsigned short* __restrict__ Wp, const float* __restrict__ bp,
    const unsigned short* __restrict__ yb, float* __restrict__ out)
{
    __shared__ unsigned short As[BM * BKK];
    __shared__ unsigned short Bs[BN * BKK];
    int tid  = threadIdx.x;
    int bidx = blockIdx.x;
    int mtile = bidx & 7, ntile = bidx >> 3;
    int mbase = mtile * BM, nbase = ntile * BN;
    int lane = tid & 63;
    int wv = tid >> 6;
    int wr = wv >> 1, wc = wv & 1;
    int lrow = lane & 15;
    int lk = (lane >> 4) * 8;

    f32x4 acc[4][4];
#pragma unroll
    for (int m = 0; m < 4; ++m)
#pragma unroll
        for (int n = 0; n < 4; ++n) { f32x4 z = {0.f,0.f,0.f,0.f}; acc[m][n] = z; }

    for (int kk = 0; kk < HH; kk += BKK) {
#pragma unroll
        for (int p = 0; p < 2; ++p) {
            int chunk = p * 256 + tid;
            int row = chunk >> 2;
            int kc  = (chunk & 3) * 8;
            gload_lds16(Wp + (size_t)(mbase + row) * HH + kk + kc, &As[chunk * 8]);
            gload_lds16(yb + (size_t)(nbase + row) * HH + kk + kc, &Bs[chunk * 8]);
        }
        __syncthreads();
        bf16x8 af[4], bfr[4];
#pragma unroll
        for (int m = 0; m < 4; ++m)
            af[m] = *(const bf16x8*)&As[(wr * 64 + m * 16 + lrow) * BKK + lk];
#pragma unroll
        for (int nf = 0; nf < 4; ++nf)
            bfr[nf] = *(const bf16x8*)&Bs[(wc * 64 + nf * 16 + lrow) * BKK + lk];
#pragma unroll
        for (int m = 0; m < 4; ++m)
#pragma unroll
            for (int nf = 0; nf < 4; ++nf)
                acc[m][nf] = __builtin_amdgcn_mfma_f32_16x16x32_bf16(af[m], bfr[nf], acc[m][nf], 0, 0, 0);
        __syncthreads();
    }
#pragma unroll
    for (int m = 0; m < 4; ++m) {
        int go = mbase + wr * 64 + m * 16 + ((lane >> 4) * 4);
        float4 bv = *(const float4*)(bp + go);
#pragma unroll
        for (int nf = 0; nf < 4; ++nf) {
            int col  = nbase + wc * 64 + nf * 16 + lrow;
            int bcol = col >> 12;
            int lcol = col & (LL - 1);
            f32x4 v = acc[m][nf];
            float a0 = v[0] + bv.x, g0 = v[1] + bv.y;
            float a1 = v[2] + bv.z, g1 = v[3] + bv.w;
            float o0 = a0 / (1.0f + __expf(-g0));
            float o1 = a1 / (1.0f + __expf(-g1));
            size_t ob = ((size_t)bcol * HH + (size_t)(go >> 1)) * LL + lcol;
            out[ob] = o0;
            out[ob + LL] = o1;
        }
    }
}

extern "C" void kernel_launch(void* const* d_in, const int* in_sizes, int n_in,
                              void* d_out, int out_size, void* d_ws, size_t ws_size,
                              hipStream_t stream) {
    const float* u    = (const float*)d_in[0];
    const float* C    = (const float*)d_in[1];
    const float* ldt  = (const float*)d_in[2];
    const float* lar  = (const float*)d_in[3];
    const float* aim  = (const float*)d_in[4];
    const float* Dv   = (const float*)d_in[5];
    const float* W    = (const float*)d_in[6];
    const float* bias = (const float*)d_in[7];
    float* out = (float*)d_out;

    // ws layout (~78.4 MB)
    char* w = (char*)d_ws;
    float* c2R = (float*)w; w += (size_t)HH * NH * 4;
    float* c2I = (float*)w; w += (size_t)HH * NH * 4;
    float* ltR = (float*)w; w += (size_t)HH * NH * 4;
    float* ltI = (float*)w; w += (size_t)HH * NH * 4;
    float* xrA = (float*)w; w += (size_t)HH * NH * 4;
    float* xiA = (float*)w; w += (size_t)HH * NH * 4;
    float* bp  = (float*)w; w += (size_t)2 * HH * 4;
    unsigned short* Wp   = (unsigned short*)w; w += (size_t)2 * HH * HH * 2;
    unsigned short* Apan = (unsigned short*)w; w += (size_t)HH * TCH * KA * 2;   // 8MB
    unsigned short* Vpan = (unsigned short*)w; w += (size_t)HH * TCH * TCH * 2;  // 4MB
    unsigned short* yb   = (unsigned short*)w; w += (size_t)BB * LL * HH * 2;    // 64MB

    // E/S buffer (64MB bf16) lives in d_out: dead before k4, k4 overwrites out fully.
    unsigned short* ES = (unsigned short*)d_out;

    k0_params<<<dim3(64),   dim3(256), 0, stream>>>(C, ldt, lar, aim, c2R, c2I, ltR, ltI, xrA, xiA);
    kw_pack  <<<dim3(256),  dim3(256), 0, stream>>>(W, bias, Wp, bp);
    kA_build <<<dim3(512),  dim3(64),  0, stream>>>(c2R, c2I, xrA, xiA, Apan, Vpan);
    kB_estate<<<dim3(2048), dim3(256), 0, stream>>>(u, Vpan, ES);
    kC_scan  <<<dim3(1024), dim3(256), 0, stream>>>(ltR, ltI, ES);
    kD_y     <<<dim3(2048), dim3(256), 0, stream>>>(u, Apan, ES, Dv, yb);
    k4_gemm  <<<dim3(4096), dim3(256), 0, stream>>>(Wp, bp, yb, out);
}

// Round 3
// 244.628 us; speedup vs baseline: 2.6196x; 2.6196x over previous
//
#include <hip/hip_runtime.h>

#define BB 16
#define HH 512
#define NH 32          // complex modes per h
#define LL 4096
#define TCH 64         // chunk length
#define NCH 64         // LL/TCH chunks per sequence
#define KA 128         // A-panel K: 64 u-taps + 64 state components

static_assert(TCH * NCH == LL, "chunking");

typedef __attribute__((ext_vector_type(8))) short bf16x8;
typedef __attribute__((ext_vector_type(4))) float f32x4;

// RNE float->bf16 bits
static __device__ __forceinline__ unsigned short f2bf(float x) {
    unsigned int u = __builtin_bit_cast(unsigned int, x);
    u = (u + 0x7fffu + ((u >> 16) & 1u)) >> 16;
    return (unsigned short)u;
}
static __device__ __forceinline__ float bf2f(unsigned short b) {
    return __builtin_bit_cast(float, ((unsigned)b) << 16);
}
static __device__ __forceinline__ unsigned pack2(float a, float b) {
    return (unsigned)f2bf(a) | ((unsigned)f2bf(b) << 16);
}

static __device__ __forceinline__ void gload_lds16(const void* g, void* l) {
#if __has_builtin(__builtin_amdgcn_global_load_lds)
    __builtin_amdgcn_global_load_lds(
        (const __attribute__((address_space(1))) unsigned int*)g,
        (__attribute__((address_space(3))) unsigned int*)l, 16, 0, 0);
#else
    *(uint4*)l = *(const uint4*)g;
#endif
}

// ---------------- k0: SSM scalar parameters ----------------
__global__ void k0_params(const float* __restrict__ C,
                          const float* __restrict__ log_dt,
                          const float* __restrict__ lAr,
                          const float* __restrict__ Aim,
                          float* __restrict__ c2R,  float* __restrict__ c2I,
                          float* __restrict__ ltR,  float* __restrict__ ltI,
                          float* __restrict__ xrA,  float* __restrict__ xiA)
{
    int tid = blockIdx.x * 256 + threadIdx.x;
    if (tid >= HH * NH) return;
    int h = tid >> 5;
    float dt = expf(log_dt[h]);
    float Ar = -expf(lAr[tid]);
    float Ai = Aim[tid];
    float xr = Ar * dt, xi = Ai * dt;      // log Lambda
    xrA[tid] = xr; xiA[tid] = xi;
    float er = expf(xr);
    float lr = er * cosf(xi);
    float li = er * sinf(xi);
    float wr = lr - 1.0f, wi = li;
    float inv = 1.0f / (Ar * Ar + Ai * Ai);
    float qr = (wr * Ar + wi * Ai) * inv;   // (Lam-1)/A
    float qi = (wi * Ar - wr * Ai) * inv;
    float cr = C[2 * tid], ci = C[2 * tid + 1];
    c2R[tid] =  2.0f * (cr * qr - ci * qi); // y = c2R*Re(s) + c2I*Im(s)
    c2I[tid] = -2.0f * (cr * qi + ci * qr);
    float eT = expf((float)TCH * xr);       // Lambda^TCH
    float aT = (float)TCH * xi;
    ltR[tid] = eT * cosf(aT);
    ltI[tid] = eT * sinf(aT);
}

// ---------------- kw: pack W (row-permuted for GLU) + bias ----------------
__global__ void kw_pack(const float* __restrict__ W, const float* __restrict__ bias,
                        unsigned short* __restrict__ Wp, float* __restrict__ bp)
{
    int tid = blockIdx.x * 256 + threadIdx.x;      // 65536
    int drow = tid >> 6;
    int kc = (tid & 63) * 8;
    int src = (drow & 1) ? (drow >> 1) + HH : (drow >> 1);
    const float4* s = (const float4*)(W + (size_t)src * HH + kc);
    float4 a = s[0], b4 = s[1];
    uint4 pack;
    pack.x = pack2(a.x, a.y);
    pack.y = pack2(a.z, a.w);
    pack.z = pack2(b4.x, b4.y);
    pack.w = pack2(b4.z, b4.w);
    *(uint4*)(Wp + (size_t)drow * HH + kc) = pack;
    if (tid < 2 * HH)
        bp[tid] = bias[(tid & 1) ? (tid >> 1) + HH : (tid >> 1)];
}

// ---------------- kA: build per-h matrices M|G (Apan) and V (Vpan) ----------------
__global__ __launch_bounds__(64) void kA_build(
    const float* __restrict__ c2R, const float* __restrict__ c2I,
    const float* __restrict__ xrA, const float* __restrict__ xiA,
    unsigned short* __restrict__ Apan, unsigned short* __restrict__ Vpan)
{
    int h = blockIdx.x;
    int t = threadIdx.x;                  // 0..63
    __shared__ float s_xr[NH], s_xi[NH], s_cr[NH], s_ci[NH], s_k[TCH];
    if (t < NH) {
        s_xr[t] = xrA[h * NH + t]; s_xi[t] = xiA[h * NH + t];
        s_cr[t] = c2R[h * NH + t]; s_ci[t] = c2I[h * NH + t];
    }
    __syncthreads();
    {
        float d = (float)t;
        float acc = 0.f;
#pragma unroll
        for (int n = 0; n < NH; ++n) {
            float er = __expf(s_xr[n] * d);
            float sv, cv; __sincosf(s_xi[n] * d, &sv, &cv);
            acc = fmaf(s_cr[n], er * cv, fmaf(s_ci[n], er * sv, acc));
        }
        s_k[t] = acc;
    }
    __syncthreads();
    unsigned short row[KA];
#pragma unroll
    for (int tau = 0; tau < TCH; ++tau)
        row[tau] = f2bf((tau <= t) ? s_k[t - tau] : 0.f);
    float tp = (float)(t + 1);
#pragma unroll
    for (int n = 0; n < NH; ++n) {
        float er = __expf(s_xr[n] * tp);
        float sv, cv; __sincosf(s_xi[n] * tp, &sv, &cv);
        float pr = er * cv, pi = er * sv;           // Lam^{t+1}
        row[TCH + 2 * n]     = f2bf(fmaf(s_cr[n], pr,  s_ci[n] * pi));
        row[TCH + 2 * n + 1] = f2bf(fmaf(s_ci[n], pr, -s_cr[n] * pi));
    }
    {
        uint4* dst = (uint4*)(Apan + ((size_t)h * TCH + t) * KA);
        const uint4* src = (const uint4*)row;
#pragma unroll
        for (int i = 0; i < 16; ++i) dst[i] = src[i];
    }
    {
        int n = t >> 1, cm = t & 1;
        float xr = s_xr[n], xi = s_xi[n];
        unsigned short vrow[TCH];
#pragma unroll
        for (int tau = 0; tau < TCH; ++tau) {
            float p = (float)(TCH - 1 - tau);
            float er = __expf(xr * p);
            float sv, cv; __sincosf(xi * p, &sv, &cv);
            vrow[tau] = f2bf(cm ? er * sv : er * cv);
        }
        uint4* vd = (uint4*)(Vpan + ((size_t)h * TCH + t) * TCH);
        const uint4* vs = (const uint4*)vrow;
#pragma unroll
        for (int i = 0; i < 8; ++i) vd[i] = vs[i];
    }
}

// ---------------- kBCD: fused E-GEMM + inter-chunk scan + Y-GEMM + GELU ----------------
// Per wave: one (b,h). Output yb in natural [b][h][l] layout (coalesced).
__global__ __launch_bounds__(256, 2) void kBCD(
    const float* __restrict__ u,
    const unsigned short* __restrict__ Apan, const unsigned short* __restrict__ Vpan,
    const float* __restrict__ ltR, const float* __restrict__ ltI,
    const float* __restrict__ Dv,
    unsigned short* __restrict__ yb)
{
    __shared__ unsigned short As_[TCH * KA];     // 16KB [t][k] swizzled, 256B rows
    __shared__ unsigned short Vs[TCH * TCH];     // 8KB  [j][tau] swizzled, 128B rows
    __shared__ unsigned short Sl[4][TCH * TCH];  // 4 waves x 8KB [c][j] swizzled
    int h = blockIdx.x & (HH - 1), g = blockIdx.x >> 9;
    int tid = threadIdx.x;
    // ---- stage A-panel (M|G) and V-panel, block-cooperative
    {
        int row = tid >> 2, part = tid & 3;      // 64B per thread
        const uint4* src = (const uint4*)(Apan + ((size_t)h * TCH + row) * KA + part * 32);
        uint4 v0 = src[0], v1 = src[1], v2 = src[2], v3 = src[3];
        char* rb = (char*)As_ + row * 256;
        int b0 = part * 64, sw = (row & 7) << 4;
        *(uint4*)(rb + ((b0)      ^ sw)) = v0;
        *(uint4*)(rb + ((b0 + 16) ^ sw)) = v1;
        *(uint4*)(rb + ((b0 + 32) ^ sw)) = v2;
        *(uint4*)(rb + ((b0 + 48) ^ sw)) = v3;
    }
    {
        int row = tid >> 2, part = tid & 3;      // 32B per thread
        const uint4* src = (const uint4*)(Vpan + ((size_t)h * TCH + row) * TCH + part * 16);
        uint4 a = src[0], b4 = src[1];
        char* rb = (char*)Vs + row * 128;
        int b0 = part * 32, sw = (row & 7) << 4;
        *(uint4*)(rb + ((b0)      ^ sw)) = a;
        *(uint4*)(rb + ((b0 + 16) ^ sw)) = b4;
    }
    __syncthreads();

    int lane = tid & 63, w = tid >> 6;
    int b = g * 4 + w;
    int lrow = lane & 15, hi = lane >> 4, lk8 = hi * 8;
    const float* ug = u + ((size_t)b * HH + h) * LL;
    char* Sw = (char*)Sl[w];

    // ---- load u once, convert to bf16 B-fragments (shared by E- and Y-GEMM)
    bf16x8 ub[2][4];
#pragma unroll
    for (int ks = 0; ks < 2; ++ks)
#pragma unroll
        for (int n = 0; n < 4; ++n) {
            int c = n * 16 + lrow;
            const float* up = ug + c * TCH + ks * 32 + lk8;
            float4 f0 = *(const float4*)up, f1 = *(const float4*)(up + 4);
            bf16x8 v;
            v[0]=f2bf(f0.x); v[1]=f2bf(f0.y); v[2]=f2bf(f0.z); v[3]=f2bf(f0.w);
            v[4]=f2bf(f1.x); v[5]=f2bf(f1.y); v[6]=f2bf(f1.z); v[7]=f2bf(f1.w);
            ub[ks][n] = v;
        }

    // ---- E-GEMM: E[j][c] = sum_tau V[j][tau] * u[c][tau]
    f32x4 accE[4][4];
#pragma unroll
    for (int m = 0; m < 4; ++m)
#pragma unroll
        for (int n = 0; n < 4; ++n) { f32x4 z = {0.f,0.f,0.f,0.f}; accE[m][n] = z; }
#pragma unroll
    for (int ks = 0; ks < 2; ++ks)
#pragma unroll
        for (int m = 0; m < 4; ++m) {
            int row = m * 16 + lrow;
            int bo = (ks * 32 + lk8) * 2;
            bf16x8 af = *(const bf16x8*)((char*)Vs + row * 128 + (bo ^ ((row & 7) << 4)));
#pragma unroll
            for (int n = 0; n < 4; ++n)
                accE[m][n] = __builtin_amdgcn_mfma_f32_16x16x32_bf16(af, ub[ks][n], accE[m][n], 0, 0, 0);
        }
    // ---- E -> per-wave LDS tile [c][j] (bf16, XOR-swizzled)
#pragma unroll
    for (int m = 0; m < 4; ++m) {
        int j0 = m * 16 + hi * 4;
#pragma unroll
        for (int n = 0; n < 4; ++n) {
            int c = n * 16 + lrow;
            f32x4 v = accE[m][n];
            uint2 p; p.x = pack2(v[0], v[1]); p.y = pack2(v[2], v[3]);
            *(uint2*)(Sw + c * 128 + ((2 * j0) ^ ((c & 7) << 4))) = p;
        }
    }
    asm volatile("s_waitcnt lgkmcnt(0)" ::: "memory");

    // ---- inter-chunk scan: lane = component j; S_{c+1} = Lam^64*S_c + E_c
    {
        int j = lane;
        int nn = j >> 1;
        float ar = ltR[h * NH + nn], ai = ltI[h * NH + nn];
        float ais = (j & 1) ? ai : -ai;   // even j=Re: -ai*Im ; odd j=Im: +ai*Re
        float s = 0.f;
        for (int c = 0; c < NCH; ++c) {
            char* p = Sw + c * 128 + ((2 * j) ^ ((c & 7) << 4));
            float e = bf2f(*(const unsigned short*)p);
            float ps = __shfl_xor(s, 1, 64);
            *(unsigned short*)p = f2bf(s);           // store entry state S_c
            s = fmaf(ar, s, fmaf(ais, ps, e));
        }
    }
    asm volatile("s_waitcnt lgkmcnt(0)" ::: "memory");

    // ---- Y-GEMM: Y[t][c] = sum_k [M|G][t][k] * { u[c][k] (k<64) ; S[c][k-64] }
    f32x4 acc[4][4];
#pragma unroll
    for (int m = 0; m < 4; ++m)
#pragma unroll
        for (int n = 0; n < 4; ++n) { f32x4 z = {0.f,0.f,0.f,0.f}; acc[m][n] = z; }
#pragma unroll
    for (int ks = 0; ks < 2; ++ks)
#pragma unroll
        for (int m = 0; m < 4; ++m) {
            int row = m * 16 + lrow;
            int bo = (ks * 32 + lk8) * 2;
            bf16x8 af = *(const bf16x8*)((char*)As_ + row * 256 + (bo ^ ((row & 7) << 4)));
#pragma unroll
            for (int n = 0; n < 4; ++n)
                acc[m][n] = __builtin_amdgcn_mfma_f32_16x16x32_bf16(af, ub[ks][n], acc[m][n], 0, 0, 0);
        }
#pragma unroll
    for (int ks = 2; ks < 4; ++ks) {
        bf16x8 bfr[4];
#pragma unroll
        for (int n = 0; n < 4; ++n) {
            int c = n * 16 + lrow;
            int bo = (ks - 2) * 64 + lk8 * 2;
            bfr[n] = *(const bf16x8*)(Sw + c * 128 + (bo ^ ((c & 7) << 4)));
        }
#pragma unroll
        for (int m = 0; m < 4; ++m) {
            int row = m * 16 + lrow;
            int bo = (ks * 32 + lk8) * 2;
            bf16x8 af = *(const bf16x8*)((char*)As_ + row * 256 + (bo ^ ((row & 7) << 4)));
#pragma unroll
            for (int n = 0; n < 4; ++n)
                acc[m][n] = __builtin_amdgcn_mfma_f32_16x16x32_bf16(af, bfr[n], acc[m][n], 0, 0, 0);
        }
    }
    // ---- epilogue: + D*u (fp32), GELU, coalesced store to yb[b][h][l]
    float Dh = Dv[h];
    unsigned short* yrow = yb + ((size_t)b * HH + h) * LL;
#pragma unroll
    for (int m = 0; m < 4; ++m) {
        int t0 = m * 16 + hi * 4;
#pragma unroll
        for (int n = 0; n < 4; ++n) {
            int c = n * 16 + lrow;
            float4 uv = *(const float4*)(ug + c * TCH + t0);
            f32x4 v = acc[m][n];
            float uu[4] = {uv.x, uv.y, uv.z, uv.w};
            unsigned short o[4];
#pragma unroll
            for (int r = 0; r < 4; ++r) {
                float yo = fmaf(Dh, uu[r], v[r]);
                float ge = 0.5f * yo * (1.0f + erff(yo * 0.70710678118f));
                o[r] = f2bf(ge);
            }
            uint2 pw;
            pw.x = (unsigned)o[0] | ((unsigned)o[1] << 16);
            pw.y = (unsigned)o[2] | ((unsigned)o[3] << 16);
            *(uint2*)(yrow + c * TCH + t0) = pw;
        }
    }
}

// ---------------- kT: transpose yb [b][h][l] -> yt [b*l][h] ----------------
__global__ __launch_bounds__(256) void kT_transpose(
    const unsigned short* __restrict__ yb, unsigned short* __restrict__ yt)
{
    __shared__ unsigned short T[64][130];        // stride 130 u16 -> 2-way max
    int bid = blockIdx.x;
    int lt = bid & 31;            // l-tile of 128
    int ht = (bid >> 5) & 7;      // h-tile of 64
    int b  = bid >> 8;
    int t = threadIdx.x;
#pragma unroll
    for (int r = 0; r < 4; ++r) {
        int chunk = r * 256 + t;                 // 1024 x 16B chunks
        int row = chunk >> 4;
        int c16 = chunk & 15;
        uint4 v = *(const uint4*)(yb + ((size_t)(b * HH + ht * 64 + row)) * LL
                                     + lt * 128 + c16 * 8);
        *(uint4*)&T[row][c16 * 8] = v;
    }
    __syncthreads();
    int oct = t & 7, lgrp = t >> 3;
    size_t obase = ((size_t)b * LL + (size_t)lt * 128) * HH + ht * 64 + oct * 8;
#pragma unroll
    for (int r = 0; r < 2; ++r) {
        int l = (r * 32 + lgrp) * 2;
        unsigned v[8];
#pragma unroll
        for (int k = 0; k < 8; ++k)
            v[k] = *(const unsigned*)&T[oct * 8 + k][l];
        uint4 w0, w1;
        w0.x = (v[0] & 0xffffu) | (v[1] << 16);
        w0.y = (v[2] & 0xffffu) | (v[3] << 16);
        w0.z = (v[4] & 0xffffu) | (v[5] << 16);
        w0.w = (v[6] & 0xffffu) | (v[7] << 16);
        w1.x = (v[0] >> 16) | (v[1] & 0xffff0000u);
        w1.y = (v[2] >> 16) | (v[3] & 0xffff0000u);
        w1.z = (v[4] >> 16) | (v[5] & 0xffff0000u);
        w1.w = (v[6] >> 16) | (v[7] & 0xffff0000u);
        *(uint4*)(yt + obase + (size_t)l * HH) = w0;
        *(uint4*)(yt + obase + (size_t)(l + 1) * HH) = w1;
    }
}

// ---------------- k4: GEMM z = Wp*y + bp, fused GLU (unchanged, known-good) ----------------
#define BM 128
#define BN 128
#define BKK 32

__global__ __launch_bounds__(256, 2) void k4_gemm(
    const unsigned short* __restrict__ Wp, const float* __restrict__ bp,
    const unsigned short* __restrict__ yt, float* __restrict__ out)
{
    __shared__ unsigned short As[BM * BKK];
    __shared__ unsigned short Bs[BN * BKK];
    int tid  = threadIdx.x;
    int bidx = blockIdx.x;
    int mtile = bidx & 7, ntile = bidx >> 3;
    int mbase = mtile * BM, nbase = ntile * BN;
    int lane = tid & 63;
    int wv = tid >> 6;
    int wr = wv >> 1, wc = wv & 1;
    int lrow = lane & 15;
    int lk = (lane >> 4) * 8;

    f32x4 acc[4][4];
#pragma unroll
    for (int m = 0; m < 4; ++m)
#pragma unroll
        for (int n = 0; n < 4; ++n) { f32x4 z = {0.f,0.f,0.f,0.f}; acc[m][n] = z; }

    for (int kk = 0; kk < HH; kk += BKK) {
#pragma unroll
        for (int p = 0; p < 2; ++p) {
            int chunk = p * 256 + tid;
            int row = chunk >> 2;
            int kc  = (chunk & 3) * 8;
            gload_lds16(Wp + (size_t)(mbase + row) * HH + kk + kc, &As[chunk * 8]);
            gload_lds16(yt + (size_t)(nbase + row) * HH + kk + kc, &Bs[chunk * 8]);
        }
        __syncthreads();
        bf16x8 af[4], bfr[4];
#pragma unroll
        for (int m = 0; m < 4; ++m)
            af[m] = *(const bf16x8*)&As[(wr * 64 + m * 16 + lrow) * BKK + lk];
#pragma unroll
        for (int nf = 0; nf < 4; ++nf)
            bfr[nf] = *(const bf16x8*)&Bs[(wc * 64 + nf * 16 + lrow) * BKK + lk];
#pragma unroll
        for (int m = 0; m < 4; ++m)
#pragma unroll
            for (int nf = 0; nf < 4; ++nf)
                acc[m][nf] = __builtin_amdgcn_mfma_f32_16x16x32_bf16(af[m], bfr[nf], acc[m][nf], 0, 0, 0);
        __syncthreads();
    }
#pragma unroll
    for (int m = 0; m < 4; ++m) {
        int go = mbase + wr * 64 + m * 16 + ((lane >> 4) * 4);
        float4 bv = *(const float4*)(bp + go);
#pragma unroll
        for (int nf = 0; nf < 4; ++nf) {
            int col  = nbase + wc * 64 + nf * 16 + lrow;
            int bcol = col >> 12;
            int lcol = col & (LL - 1);
            f32x4 v = acc[m][nf];
            float a0 = v[0] + bv.x, g0 = v[1] + bv.y;
            float a1 = v[2] + bv.z, g1 = v[3] + bv.w;
            float o0 = a0 / (1.0f + __expf(-g0));
            float o1 = a1 / (1.0f + __expf(-g1));
            size_t ob = ((size_t)bcol * HH + (size_t)(go >> 1)) * LL + lcol;
            out[ob] = o0;
            out[ob + LL] = o1;
        }
    }
}

extern "C" void kernel_launch(void* const* d_in, const int* in_sizes, int n_in,
                              void* d_out, int out_size, void* d_ws, size_t ws_size,
                              hipStream_t stream) {
    const float* u    = (const float*)d_in[0];
    const float* C    = (const float*)d_in[1];
    const float* ldt  = (const float*)d_in[2];
    const float* lar  = (const float*)d_in[3];
    const float* aim  = (const float*)d_in[4];
    const float* Dv   = (const float*)d_in[5];
    const float* W    = (const float*)d_in[6];
    const float* bias = (const float*)d_in[7];
    float* out = (float*)d_out;

    // ws layout (~79 MB)
    char* w = (char*)d_ws;
    float* c2R = (float*)w; w += (size_t)HH * NH * 4;
    float* c2I = (float*)w; w += (size_t)HH * NH * 4;
    float* ltR = (float*)w; w += (size_t)HH * NH * 4;
    float* ltI = (float*)w; w += (size_t)HH * NH * 4;
    float* xrA = (float*)w; w += (size_t)HH * NH * 4;
    float* xiA = (float*)w; w += (size_t)HH * NH * 4;
    float* bp  = (float*)w; w += (size_t)2 * HH * 4;
    unsigned short* Wp   = (unsigned short*)w; w += (size_t)2 * HH * HH * 2;
    unsigned short* Apan = (unsigned short*)w; w += (size_t)HH * TCH * KA * 2;   // 8MB
    unsigned short* Vpan = (unsigned short*)w; w += (size_t)HH * TCH * TCH * 2;  // 4MB
    unsigned short* yt   = (unsigned short*)w; w += (size_t)BB * LL * HH * 2;    // 64MB

    // yb (pre-transpose, 64MB bf16) lives in d_out (134MB): dead before k4,
    // kT consumes it before k4 overwrites out.
    unsigned short* yb = (unsigned short*)d_out;

    k0_params   <<<dim3(64),   dim3(256), 0, stream>>>(C, ldt, lar, aim, c2R, c2I, ltR, ltI, xrA, xiA);
    kw_pack     <<<dim3(256),  dim3(256), 0, stream>>>(W, bias, Wp, bp);
    kA_build    <<<dim3(512),  dim3(64),  0, stream>>>(c2R, c2I, xrA, xiA, Apan, Vpan);
    kBCD        <<<dim3(2048), dim3(256), 0, stream>>>(u, Apan, Vpan, ltR, ltI, Dv, yb);
    kT_transpose<<<dim3(4096), dim3(256), 0, stream>>>(yb, yt);
    k4_gemm     <<<dim3(4096), dim3(256), 0, stream>>>(Wp, bp, yt, out);
}

// Round 4
// 235.058 us; speedup vs baseline: 2.7263x; 1.0407x over previous
//
#include <hip/hip_runtime.h>

#define BB 16
#define HH 512
#define NH 32          // complex modes per h
#define LL 4096
#define TCH 64         // chunk length
#define NCH 64         // LL/TCH chunks per sequence
#define KA 128         // A-panel K: 64 u-taps + 64 state components

static_assert(TCH * NCH == LL, "chunking");

typedef __attribute__((ext_vector_type(8))) short bf16x8;
typedef __attribute__((ext_vector_type(4))) float f32x4;

// RNE float->bf16 bits
static __device__ __forceinline__ unsigned short f2bf(float x) {
    unsigned int u = __builtin_bit_cast(unsigned int, x);
    u = (u + 0x7fffu + ((u >> 16) & 1u)) >> 16;
    return (unsigned short)u;
}
static __device__ __forceinline__ float bf2f(unsigned short b) {
    return __builtin_bit_cast(float, ((unsigned)b) << 16);
}
static __device__ __forceinline__ unsigned pack2(float a, float b) {
    return (unsigned)f2bf(a) | ((unsigned)f2bf(b) << 16);
}

static __device__ __forceinline__ void gload_lds16(const void* g, void* l) {
#if __has_builtin(__builtin_amdgcn_global_load_lds)
    __builtin_amdgcn_global_load_lds(
        (const __attribute__((address_space(1))) unsigned int*)g,
        (__attribute__((address_space(3))) unsigned int*)l, 16, 0, 0);
#else
    *(uint4*)l = *(const uint4*)g;
#endif
}

// ---------------- k0: SSM scalar parameters ----------------
__global__ void k0_params(const float* __restrict__ C,
                          const float* __restrict__ log_dt,
                          const float* __restrict__ lAr,
                          const float* __restrict__ Aim,
                          float* __restrict__ c2R,  float* __restrict__ c2I,
                          float* __restrict__ ltR,  float* __restrict__ ltI,
                          float* __restrict__ xrA,  float* __restrict__ xiA)
{
    int tid = blockIdx.x * 256 + threadIdx.x;
    if (tid >= HH * NH) return;
    int h = tid >> 5;
    float dt = expf(log_dt[h]);
    float Ar = -expf(lAr[tid]);
    float Ai = Aim[tid];
    float xr = Ar * dt, xi = Ai * dt;      // log Lambda
    xrA[tid] = xr; xiA[tid] = xi;
    float er = expf(xr);
    float lr = er * cosf(xi);
    float li = er * sinf(xi);
    float wr = lr - 1.0f, wi = li;
    float inv = 1.0f / (Ar * Ar + Ai * Ai);
    float qr = (wr * Ar + wi * Ai) * inv;   // (Lam-1)/A
    float qi = (wi * Ar - wr * Ai) * inv;
    float cr = C[2 * tid], ci = C[2 * tid + 1];
    c2R[tid] =  2.0f * (cr * qr - ci * qi); // y = c2R*Re(s) + c2I*Im(s)
    c2I[tid] = -2.0f * (cr * qi + ci * qr);
    float eT = expf((float)TCH * xr);       // Lambda^TCH
    float aT = (float)TCH * xi;
    ltR[tid] = eT * cosf(aT);
    ltI[tid] = eT * sinf(aT);
}

// ---------------- kw: pack W (row-permuted for GLU) + bias ----------------
__global__ void kw_pack(const float* __restrict__ W, const float* __restrict__ bias,
                        unsigned short* __restrict__ Wp, float* __restrict__ bp)
{
    int tid = blockIdx.x * 256 + threadIdx.x;      // 65536
    int drow = tid >> 6;
    int kc = (tid & 63) * 8;
    int src = (drow & 1) ? (drow >> 1) + HH : (drow >> 1);
    const float4* s = (const float4*)(W + (size_t)src * HH + kc);
    float4 a = s[0], b4 = s[1];
    uint4 pack;
    pack.x = pack2(a.x, a.y);
    pack.y = pack2(a.z, a.w);
    pack.z = pack2(b4.x, b4.y);
    pack.w = pack2(b4.z, b4.w);
    *(uint4*)(Wp + (size_t)drow * HH + kc) = pack;
    if (tid < 2 * HH)
        bp[tid] = bias[(tid & 1) ? (tid >> 1) + HH : (tid >> 1)];
}

// ---------------- kA: build per-h matrices M|G (Apan) and V (Vpan) ----------------
__global__ __launch_bounds__(64) void kA_build(
    const float* __restrict__ c2R, const float* __restrict__ c2I,
    const float* __restrict__ xrA, const float* __restrict__ xiA,
    unsigned short* __restrict__ Apan, unsigned short* __restrict__ Vpan)
{
    int h = blockIdx.x;
    int t = threadIdx.x;                  // 0..63
    __shared__ float s_xr[NH], s_xi[NH], s_cr[NH], s_ci[NH], s_k[TCH];
    if (t < NH) {
        s_xr[t] = xrA[h * NH + t]; s_xi[t] = xiA[h * NH + t];
        s_cr[t] = c2R[h * NH + t]; s_ci[t] = c2I[h * NH + t];
    }
    __syncthreads();
    {
        float d = (float)t;
        float acc = 0.f;
#pragma unroll
        for (int n = 0; n < NH; ++n) {
            float er = __expf(s_xr[n] * d);
            float sv, cv; __sincosf(s_xi[n] * d, &sv, &cv);
            acc = fmaf(s_cr[n], er * cv, fmaf(s_ci[n], er * sv, acc));
        }
        s_k[t] = acc;
    }
    __syncthreads();
    unsigned short row[KA];
#pragma unroll
    for (int tau = 0; tau < TCH; ++tau)
        row[tau] = f2bf((tau <= t) ? s_k[t - tau] : 0.f);
    float tp = (float)(t + 1);
#pragma unroll
    for (int n = 0; n < NH; ++n) {
        float er = __expf(s_xr[n] * tp);
        float sv, cv; __sincosf(s_xi[n] * tp, &sv, &cv);
        float pr = er * cv, pi = er * sv;           // Lam^{t+1}
        row[TCH + 2 * n]     = f2bf(fmaf(s_cr[n], pr,  s_ci[n] * pi));
        row[TCH + 2 * n + 1] = f2bf(fmaf(s_ci[n], pr, -s_cr[n] * pi));
    }
    {
        uint4* dst = (uint4*)(Apan + ((size_t)h * TCH + t) * KA);
        const uint4* src = (const uint4*)row;
#pragma unroll
        for (int i = 0; i < 16; ++i) dst[i] = src[i];
    }
    {
        int n = t >> 1, cm = t & 1;
        float xr = s_xr[n], xi = s_xi[n];
        unsigned short vrow[TCH];
#pragma unroll
        for (int tau = 0; tau < TCH; ++tau) {
            float p = (float)(TCH - 1 - tau);
            float er = __expf(xr * p);
            float sv, cv; __sincosf(xi * p, &sv, &cv);
            vrow[tau] = f2bf(cm ? er * sv : er * cv);
        }
        uint4* vd = (uint4*)(Vpan + ((size_t)h * TCH + t) * TCH);
        const uint4* vs = (const uint4*)vrow;
#pragma unroll
        for (int i = 0; i < 8; ++i) vd[i] = vs[i];
    }
}

// ---------------- kBCD: fused E-GEMM + inter-chunk scan + Y-GEMM + GELU ----------------
// Per wave: one (b,h). A/V fragments read directly from global (L1/L2-hot
// panels); LDS holds only the per-wave scan tile -> 32KB/block, no barriers.
__global__ __launch_bounds__(256, 4) void kBCD(
    const float* __restrict__ u,
    const unsigned short* __restrict__ Apan, const unsigned short* __restrict__ Vpan,
    const float* __restrict__ ltR, const float* __restrict__ ltI,
    const float* __restrict__ Dv,
    unsigned short* __restrict__ yb)
{
    __shared__ unsigned short Sl[4][TCH * TCH];  // 4 waves x 8KB [c][j] swizzled
    int h = blockIdx.x & (HH - 1), g = blockIdx.x >> 9;
    int tid = threadIdx.x;
    int lane = tid & 63, w = tid >> 6;
    int b = g * 4 + w;
    int lrow = lane & 15, hi = lane >> 4, lk8 = hi * 8;
    const float* ug = u + ((size_t)b * HH + h) * LL;
    const unsigned short* Ap = Apan + (size_t)h * TCH * KA;
    const unsigned short* Vp = Vpan + (size_t)h * TCH * TCH;
    char* Sw = (char*)Sl[w];

    // ---- load u once, convert to bf16 B-fragments (shared by E- and Y-GEMM)
    bf16x8 ub[2][4];
#pragma unroll
    for (int ks = 0; ks < 2; ++ks)
#pragma unroll
        for (int n = 0; n < 4; ++n) {
            int c = n * 16 + lrow;
            const float* up = ug + c * TCH + ks * 32 + lk8;
            float4 f0 = *(const float4*)up, f1 = *(const float4*)(up + 4);
            bf16x8 v;
            v[0]=f2bf(f0.x); v[1]=f2bf(f0.y); v[2]=f2bf(f0.z); v[3]=f2bf(f0.w);
            v[4]=f2bf(f1.x); v[5]=f2bf(f1.y); v[6]=f2bf(f1.z); v[7]=f2bf(f1.w);
            ub[ks][n] = v;
        }

    // ---- E-GEMM: E[j][c] = sum_tau V[j][tau] * u[c][tau]
    f32x4 accE[4][4];
#pragma unroll
    for (int m = 0; m < 4; ++m)
#pragma unroll
        for (int n = 0; n < 4; ++n) { f32x4 z = {0.f,0.f,0.f,0.f}; accE[m][n] = z; }
#pragma unroll
    for (int ks = 0; ks < 2; ++ks) {
        bf16x8 vf[4];
#pragma unroll
        for (int m = 0; m < 4; ++m)
            vf[m] = *(const bf16x8*)(Vp + (m * 16 + lrow) * TCH + ks * 32 + lk8);
#pragma unroll
        for (int m = 0; m < 4; ++m)
#pragma unroll
            for (int n = 0; n < 4; ++n)
                accE[m][n] = __builtin_amdgcn_mfma_f32_16x16x32_bf16(vf[m], ub[ks][n], accE[m][n], 0, 0, 0);
    }
    // ---- E -> per-wave LDS tile [c][j] (bf16, XOR-swizzled)
#pragma unroll
    for (int m = 0; m < 4; ++m) {
        int j0 = m * 16 + hi * 4;
#pragma unroll
        for (int n = 0; n < 4; ++n) {
            int c = n * 16 + lrow;
            f32x4 v = accE[m][n];
            uint2 p; p.x = pack2(v[0], v[1]); p.y = pack2(v[2], v[3]);
            *(uint2*)(Sw + c * 128 + ((2 * j0) ^ ((c & 7) << 4))) = p;
        }
    }
    asm volatile("s_waitcnt lgkmcnt(0)" ::: "memory");

    // ---- inter-chunk scan: lane = component j; S_{c+1} = Lam^64*S_c + E_c
    {
        int j = lane;
        int nn = j >> 1;
        float ar = ltR[h * NH + nn], ai = ltI[h * NH + nn];
        float ais = (j & 1) ? ai : -ai;   // even j=Re: -ai*Im ; odd j=Im: +ai*Re
        float s = 0.f;
        for (int c = 0; c < NCH; ++c) {
            char* p = Sw + c * 128 + ((2 * j) ^ ((c & 7) << 4));
            float e = bf2f(*(const unsigned short*)p);
            float ps = __shfl_xor(s, 1, 64);
            *(unsigned short*)p = f2bf(s);           // store entry state S_c
            s = fmaf(ar, s, fmaf(ais, ps, e));
        }
    }
    asm volatile("s_waitcnt lgkmcnt(0)" ::: "memory");

    // ---- Y-GEMM: Y[t][c] = sum_k [M|G][t][k] * { u[c][k] (k<64) ; S[c][k-64] }
    f32x4 acc[4][4];
#pragma unroll
    for (int m = 0; m < 4; ++m)
#pragma unroll
        for (int n = 0; n < 4; ++n) { f32x4 z = {0.f,0.f,0.f,0.f}; acc[m][n] = z; }
#pragma unroll
    for (int ks = 0; ks < 2; ++ks) {
        bf16x8 af[4];
#pragma unroll
        for (int m = 0; m < 4; ++m)
            af[m] = *(const bf16x8*)(Ap + (m * 16 + lrow) * KA + ks * 32 + lk8);
#pragma unroll
        for (int m = 0; m < 4; ++m)
#pragma unroll
            for (int n = 0; n < 4; ++n)
                acc[m][n] = __builtin_amdgcn_mfma_f32_16x16x32_bf16(af[m], ub[ks][n], acc[m][n], 0, 0, 0);
    }
#pragma unroll
    for (int ks = 2; ks < 4; ++ks) {
        bf16x8 af[4], bfr[4];
#pragma unroll
        for (int m = 0; m < 4; ++m)
            af[m] = *(const bf16x8*)(Ap + (m * 16 + lrow) * KA + ks * 32 + lk8);
#pragma unroll
        for (int n = 0; n < 4; ++n) {
            int c = n * 16 + lrow;
            int bo = (ks - 2) * 64 + lk8 * 2;
            bfr[n] = *(const bf16x8*)(Sw + c * 128 + (bo ^ ((c & 7) << 4)));
        }
#pragma unroll
        for (int m = 0; m < 4; ++m)
#pragma unroll
            for (int n = 0; n < 4; ++n)
                acc[m][n] = __builtin_amdgcn_mfma_f32_16x16x32_bf16(af[m], bfr[n], acc[m][n], 0, 0, 0);
    }
    // ---- epilogue: + D*u (fp32), GELU, coalesced store to yb[b][h][l]
    float Dh = Dv[h];
    unsigned short* yrow = yb + ((size_t)b * HH + h) * LL;
#pragma unroll
    for (int m = 0; m < 4; ++m) {
        int t0 = m * 16 + hi * 4;
#pragma unroll
        for (int n = 0; n < 4; ++n) {
            int c = n * 16 + lrow;
            float4 uv = *(const float4*)(ug + c * TCH + t0);
            f32x4 v = acc[m][n];
            float uu[4] = {uv.x, uv.y, uv.z, uv.w};
            unsigned short o[4];
#pragma unroll
            for (int r = 0; r < 4; ++r) {
                float yo = fmaf(Dh, uu[r], v[r]);
                float ge = 0.5f * yo * (1.0f + erff(yo * 0.70710678118f));
                o[r] = f2bf(ge);
            }
            uint2 pw;
            pw.x = (unsigned)o[0] | ((unsigned)o[1] << 16);
            pw.y = (unsigned)o[2] | ((unsigned)o[3] << 16);
            *(uint2*)(yrow + c * TCH + t0) = pw;
        }
    }
}

// ---------------- kT: transpose yb [b][h][l] -> yt [b*l][h] ----------------
__global__ __launch_bounds__(256) void kT_transpose(
    const unsigned short* __restrict__ yb, unsigned short* __restrict__ yt)
{
    __shared__ unsigned short T[64][130];        // stride 130 u16 -> 2-way max
    int bid = blockIdx.x;
    int lt = bid & 31;            // l-tile of 128
    int ht = (bid >> 5) & 7;      // h-tile of 64
    int b  = bid >> 8;
    int t = threadIdx.x;
#pragma unroll
    for (int r = 0; r < 4; ++r) {
        int chunk = r * 256 + t;                 // 1024 x 16B chunks
        int row = chunk >> 4;
        int c16 = chunk & 15;
        uint4 v = *(const uint4*)(yb + ((size_t)(b * HH + ht * 64 + row)) * LL
                                     + lt * 128 + c16 * 8);
        *(uint4*)&T[row][c16 * 8] = v;
    }
    __syncthreads();
    int oct = t & 7, lgrp = t >> 3;
    size_t obase = ((size_t)b * LL + (size_t)lt * 128) * HH + ht * 64 + oct * 8;
#pragma unroll
    for (int r = 0; r < 2; ++r) {
        int l = (r * 32 + lgrp) * 2;
        unsigned v[8];
#pragma unroll
        for (int k = 0; k < 8; ++k)
            v[k] = *(const unsigned*)&T[oct * 8 + k][l];
        uint4 w0, w1;
        w0.x = (v[0] & 0xffffu) | (v[1] << 16);
        w0.y = (v[2] & 0xffffu) | (v[3] << 16);
        w0.z = (v[4] & 0xffffu) | (v[5] << 16);
        w0.w = (v[6] & 0xffffu) | (v[7] << 16);
        w1.x = (v[0] >> 16) | (v[1] & 0xffff0000u);
        w1.y = (v[2] >> 16) | (v[3] & 0xffff0000u);
        w1.z = (v[4] >> 16) | (v[5] & 0xffff0000u);
        w1.w = (v[6] >> 16) | (v[7] & 0xffff0000u);
        *(uint4*)(yt + obase + (size_t)l * HH) = w0;
        *(uint4*)(yt + obase + (size_t)(l + 1) * HH) = w1;
    }
}

// ---------------- k4: GEMM z = Wp*y + bp, fused GLU (unchanged, known-good) ----------------
#define BM 128
#define BN 128
#define BKK 32

__global__ __launch_bounds__(256, 2) void k4_gemm(
    const unsigned short* __restrict__ Wp, const float* __restrict__ bp,
    const unsigned short* __restrict__ yt, float* __restrict__ out)
{
    __shared__ unsigned short As[BM * BKK];
    __shared__ unsigned short Bs[BN * BKK];
    int tid  = threadIdx.x;
    int bidx = blockIdx.x;
    int mtile = bidx & 7, ntile = bidx >> 3;
    int mbase = mtile * BM, nbase = ntile * BN;
    int lane = tid & 63;
    int wv = tid >> 6;
    int wr = wv >> 1, wc = wv & 1;
    int lrow = lane & 15;
    int lk = (lane >> 4) * 8;

    f32x4 acc[4][4];
#pragma unroll
    for (int m = 0; m < 4; ++m)
#pragma unroll
        for (int n = 0; n < 4; ++n) { f32x4 z = {0.f,0.f,0.f,0.f}; acc[m][n] = z; }

    for (int kk = 0; kk < HH; kk += BKK) {
#pragma unroll
        for (int p = 0; p < 2; ++p) {
            int chunk = p * 256 + tid;
            int row = chunk >> 2;
            int kc  = (chunk & 3) * 8;
            gload_lds16(Wp + (size_t)(mbase + row) * HH + kk + kc, &As[chunk * 8]);
            gload_lds16(yt + (size_t)(nbase + row) * HH + kk + kc, &Bs[chunk * 8]);
        }
        __syncthreads();
        bf16x8 af[4], bfr[4];
#pragma unroll
        for (int m = 0; m < 4; ++m)
            af[m] = *(const bf16x8*)&As[(wr * 64 + m * 16 + lrow) * BKK + lk];
#pragma unroll
        for (int nf = 0; nf < 4; ++nf)
            bfr[nf] = *(const bf16x8*)&Bs[(wc * 64 + nf * 16 + lrow) * BKK + lk];
#pragma unroll
        for (int m = 0; m < 4; ++m)
#pragma unroll
            for (int nf = 0; nf < 4; ++nf)
                acc[m][nf] = __builtin_amdgcn_mfma_f32_16x16x32_bf16(af[m], bfr[nf], acc[m][nf], 0, 0, 0);
        __syncthreads();
    }
#pragma unroll
    for (int m = 0; m < 4; ++m) {
        int go = mbase + wr * 64 + m * 16 + ((lane >> 4) * 4);
        float4 bv = *(const float4*)(bp + go);
#pragma unroll
        for (int nf = 0; nf < 4; ++nf) {
            int col  = nbase + wc * 64 + nf * 16 + lrow;
            int bcol = col >> 12;
            int lcol = col & (LL - 1);
            f32x4 v = acc[m][nf];
            float a0 = v[0] + bv.x, g0 = v[1] + bv.y;
            float a1 = v[2] + bv.z, g1 = v[3] + bv.w;
            float o0 = a0 / (1.0f + __expf(-g0));
            float o1 = a1 / (1.0f + __expf(-g1));
            size_t ob = ((size_t)bcol * HH + (size_t)(go >> 1)) * LL + lcol;
            out[ob] = o0;
            out[ob + LL] = o1;
        }
    }
}

extern "C" void kernel_launch(void* const* d_in, const int* in_sizes, int n_in,
                              void* d_out, int out_size, void* d_ws, size_t ws_size,
                              hipStream_t stream) {
    const float* u    = (const float*)d_in[0];
    const float* C    = (const float*)d_in[1];
    const float* ldt  = (const float*)d_in[2];
    const float* lar  = (const float*)d_in[3];
    const float* aim  = (const float*)d_in[4];
    const float* Dv   = (const float*)d_in[5];
    const float* W    = (const float*)d_in[6];
    const float* bias = (const float*)d_in[7];
    float* out = (float*)d_out;

    // ws layout (~79 MB)
    char* w = (char*)d_ws;
    float* c2R = (float*)w; w += (size_t)HH * NH * 4;
    float* c2I = (float*)w; w += (size_t)HH * NH * 4;
    float* ltR = (float*)w; w += (size_t)HH * NH * 4;
    float* ltI = (float*)w; w += (size_t)HH * NH * 4;
    float* xrA = (float*)w; w += (size_t)HH * NH * 4;
    float* xiA = (float*)w; w += (size_t)HH * NH * 4;
    float* bp  = (float*)w; w += (size_t)2 * HH * 4;
    unsigned short* Wp   = (unsigned short*)w; w += (size_t)2 * HH * HH * 2;
    unsigned short* Apan = (unsigned short*)w; w += (size_t)HH * TCH * KA * 2;   // 8MB
    unsigned short* Vpan = (unsigned short*)w; w += (size_t)HH * TCH * TCH * 2;  // 4MB
    unsigned short* yt   = (unsigned short*)w; w += (size_t)BB * LL * HH * 2;    // 64MB

    // yb (pre-transpose, 64MB bf16) lives in d_out (134MB): dead before k4,
    // kT consumes it before k4 overwrites out.
    unsigned short* yb = (unsigned short*)d_out;

    k0_params   <<<dim3(64),   dim3(256), 0, stream>>>(C, ldt, lar, aim, c2R, c2I, ltR, ltI, xrA, xiA);
    kw_pack     <<<dim3(256),  dim3(256), 0, stream>>>(W, bias, Wp, bp);
    kA_build    <<<dim3(512),  dim3(64),  0, stream>>>(c2R, c2I, xrA, xiA, Apan, Vpan);
    kBCD        <<<dim3(2048), dim3(256), 0, stream>>>(u, Apan, Vpan, ltR, ltI, Dv, yb);
    kT_transpose<<<dim3(4096), dim3(256), 0, stream>>>(yb, yt);
    k4_gemm     <<<dim3(4096), dim3(256), 0, stream>>>(Wp, bp, yt, out);
}

// Round 5
// 215.753 us; speedup vs baseline: 2.9702x; 1.0895x over previous
//
#include <hip/hip_runtime.h>

#define BB 16
#define HH 512
#define NH 32          // complex modes per h
#define LL 4096
#define TCH 64         // chunk length
#define NCH 64         // LL/TCH chunks per sequence
#define KA 128         // A-panel K: 64 u-taps + 64 state components

static_assert(TCH * NCH == LL, "chunking");

typedef __attribute__((ext_vector_type(8))) short bf16x8;
typedef __attribute__((ext_vector_type(4))) float f32x4;

// float->bf16 RNE via native convert (v_cvt_pk_bf16_f32 on gfx950)
static __device__ __forceinline__ unsigned short f2bf(float x) {
    return __builtin_bit_cast(unsigned short, (__bf16)x);
}
static __device__ __forceinline__ float bf2f(unsigned short b) {
    return __builtin_bit_cast(float, ((unsigned)b) << 16);
}
static __device__ __forceinline__ unsigned pack2(float a, float b) {
    return (unsigned)f2bf(a) | ((unsigned)f2bf(b) << 16);
}

static __device__ __forceinline__ void gload_lds16(const void* g, void* l) {
#if __has_builtin(__builtin_amdgcn_global_load_lds)
    __builtin_amdgcn_global_load_lds(
        (const __attribute__((address_space(1))) unsigned int*)g,
        (__attribute__((address_space(3))) unsigned int*)l, 16, 0, 0);
#else
    *(uint4*)l = *(const uint4*)g;
#endif
}

// ---------------- k0: SSM scalar parameters ----------------
__global__ void k0_params(const float* __restrict__ C,
                          const float* __restrict__ log_dt,
                          const float* __restrict__ lAr,
                          const float* __restrict__ Aim,
                          float* __restrict__ c2R,  float* __restrict__ c2I,
                          float* __restrict__ ltR,  float* __restrict__ ltI,
                          float* __restrict__ xrA,  float* __restrict__ xiA)
{
    int tid = blockIdx.x * 256 + threadIdx.x;
    if (tid >= HH * NH) return;
    int h = tid >> 5;
    float dt = expf(log_dt[h]);
    float Ar = -expf(lAr[tid]);
    float Ai = Aim[tid];
    float xr = Ar * dt, xi = Ai * dt;      // log Lambda
    xrA[tid] = xr; xiA[tid] = xi;
    float er = expf(xr);
    float lr = er * cosf(xi);
    float li = er * sinf(xi);
    float wr = lr - 1.0f, wi = li;
    float inv = 1.0f / (Ar * Ar + Ai * Ai);
    float qr = (wr * Ar + wi * Ai) * inv;   // (Lam-1)/A
    float qi = (wi * Ar - wr * Ai) * inv;
    float cr = C[2 * tid], ci = C[2 * tid + 1];
    c2R[tid] =  2.0f * (cr * qr - ci * qi); // y = c2R*Re(s) + c2I*Im(s)
    c2I[tid] = -2.0f * (cr * qi + ci * qr);
    float eT = expf((float)TCH * xr);       // Lambda^TCH
    float aT = (float)TCH * xi;
    ltR[tid] = eT * cosf(aT);
    ltI[tid] = eT * sinf(aT);
}

// ---------------- kw: pack W (row-permuted for GLU) + bias ----------------
__global__ void kw_pack(const float* __restrict__ W, const float* __restrict__ bias,
                        unsigned short* __restrict__ Wp, float* __restrict__ bp)
{
    int tid = blockIdx.x * 256 + threadIdx.x;      // 65536
    int drow = tid >> 6;
    int kc = (tid & 63) * 8;
    int src = (drow & 1) ? (drow >> 1) + HH : (drow >> 1);
    const float4* s = (const float4*)(W + (size_t)src * HH + kc);
    float4 a = s[0], b4 = s[1];
    uint4 pack;
    pack.x = pack2(a.x, a.y);
    pack.y = pack2(a.z, a.w);
    pack.z = pack2(b4.x, b4.y);
    pack.w = pack2(b4.z, b4.w);
    *(uint4*)(Wp + (size_t)drow * HH + kc) = pack;
    if (tid < 2 * HH)
        bp[tid] = bias[(tid & 1) ? (tid >> 1) + HH : (tid >> 1)];
}

// ---------------- kA: build per-h matrices M|G (Apan) and V (Vpan) ----------------
// M diagonal absorbs D: M'[t][t] = k[0] + D_h  (exact algebra; D*u via MFMA)
__global__ __launch_bounds__(64) void kA_build(
    const float* __restrict__ c2R, const float* __restrict__ c2I,
    const float* __restrict__ xrA, const float* __restrict__ xiA,
    const float* __restrict__ Dv,
    unsigned short* __restrict__ Apan, unsigned short* __restrict__ Vpan)
{
    int h = blockIdx.x;
    int t = threadIdx.x;                  // 0..63
    __shared__ float s_xr[NH], s_xi[NH], s_cr[NH], s_ci[NH], s_k[TCH];
    if (t < NH) {
        s_xr[t] = xrA[h * NH + t]; s_xi[t] = xiA[h * NH + t];
        s_cr[t] = c2R[h * NH + t]; s_ci[t] = c2I[h * NH + t];
    }
    __syncthreads();
    {
        float d = (float)t;
        float acc = 0.f;
#pragma unroll
        for (int n = 0; n < NH; ++n) {
            float er = __expf(s_xr[n] * d);
            float sv, cv; __sincosf(s_xi[n] * d, &sv, &cv);
            acc = fmaf(s_cr[n], er * cv, fmaf(s_ci[n], er * sv, acc));
        }
        s_k[t] = acc;
    }
    __syncthreads();
    float k0d = s_k[0] + Dv[h];
    unsigned short row[KA];
#pragma unroll
    for (int tau = 0; tau < TCH; ++tau)
        row[tau] = f2bf((tau < t) ? s_k[t - tau] : (tau == t ? k0d : 0.f));
    float tp = (float)(t + 1);
#pragma unroll
    for (int n = 0; n < NH; ++n) {
        float er = __expf(s_xr[n] * tp);
        float sv, cv; __sincosf(s_xi[n] * tp, &sv, &cv);
        float pr = er * cv, pi = er * sv;           // Lam^{t+1}
        row[TCH + 2 * n]     = f2bf(fmaf(s_cr[n], pr,  s_ci[n] * pi));
        row[TCH + 2 * n + 1] = f2bf(fmaf(s_ci[n], pr, -s_cr[n] * pi));
    }
    {
        uint4* dst = (uint4*)(Apan + ((size_t)h * TCH + t) * KA);
        const uint4* src = (const uint4*)row;
#pragma unroll
        for (int i = 0; i < 16; ++i) dst[i] = src[i];
    }
    {
        int n = t >> 1, cm = t & 1;
        float xr = s_xr[n], xi = s_xi[n];
        unsigned short vrow[TCH];
#pragma unroll
        for (int tau = 0; tau < TCH; ++tau) {
            float p = (float)(TCH - 1 - tau);
            float er = __expf(xr * p);
            float sv, cv; __sincosf(xi * p, &sv, &cv);
            vrow[tau] = f2bf(cm ? er * sv : er * cv);
        }
        uint4* vd = (uint4*)(Vpan + ((size_t)h * TCH + t) * TCH);
        const uint4* vs = (const uint4*)vrow;
#pragma unroll
        for (int i = 0; i < 8; ++i) vd[i] = vs[i];
    }
}

// ---------------- kBCD: fused E-GEMM + inter-chunk scan + Y-GEMM + GELU ----------------
// Per wave: one (b,h). A/V fragments from global (L2-hot); LDS = per-wave
// scan tile only. Scan is in-lane complex (no shfl, no LDS dep-chain).
__global__ __launch_bounds__(256, 4) void kBCD(
    const float* __restrict__ u,
    const unsigned short* __restrict__ Apan, const unsigned short* __restrict__ Vpan,
    const float* __restrict__ ltR, const float* __restrict__ ltI,
    unsigned short* __restrict__ yb)
{
    __shared__ unsigned short Sl[4][TCH * TCH];  // 4 waves x 8KB [c][j] swizzled
    int h = blockIdx.x & (HH - 1), g = blockIdx.x >> 9;
    int tid = threadIdx.x;
    int lane = tid & 63, w = tid >> 6;
    int b = g * 4 + w;
    int lrow = lane & 15, hi = lane >> 4, lk8 = hi * 8;
    const float* ug = u + ((size_t)b * HH + h) * LL;
    const unsigned short* Ap = Apan + (size_t)h * TCH * KA;
    const unsigned short* Vp = Vpan + (size_t)h * TCH * TCH;
    char* Sw = (char*)Sl[w];

    // ---- load u once, convert to bf16 B-fragments (shared by E- and Y-GEMM)
    bf16x8 ub[2][4];
#pragma unroll
    for (int ks = 0; ks < 2; ++ks)
#pragma unroll
        for (int n = 0; n < 4; ++n) {
            int c = n * 16 + lrow;
            const float* up = ug + c * TCH + ks * 32 + lk8;
            float4 f0 = *(const float4*)up, f1 = *(const float4*)(up + 4);
            bf16x8 v;
            v[0]=f2bf(f0.x); v[1]=f2bf(f0.y); v[2]=f2bf(f0.z); v[3]=f2bf(f0.w);
            v[4]=f2bf(f1.x); v[5]=f2bf(f1.y); v[6]=f2bf(f1.z); v[7]=f2bf(f1.w);
            ub[ks][n] = v;
        }

    // ---- E-GEMM: E[j][c] = sum_tau V[j][tau] * u[c][tau]
    f32x4 accE[4][4];
#pragma unroll
    for (int m = 0; m < 4; ++m)
#pragma unroll
        for (int n = 0; n < 4; ++n) { f32x4 z = {0.f,0.f,0.f,0.f}; accE[m][n] = z; }
#pragma unroll
    for (int ks = 0; ks < 2; ++ks) {
        bf16x8 vf[4];
#pragma unroll
        for (int m = 0; m < 4; ++m)
            vf[m] = *(const bf16x8*)(Vp + (m * 16 + lrow) * TCH + ks * 32 + lk8);
#pragma unroll
        for (int m = 0; m < 4; ++m)
#pragma unroll
            for (int n = 0; n < 4; ++n)
                accE[m][n] = __builtin_amdgcn_mfma_f32_16x16x32_bf16(vf[m], ub[ks][n], accE[m][n], 0, 0, 0);
    }
    // ---- E -> per-wave LDS tile [c][j] (bf16, XOR-swizzled)
#pragma unroll
    for (int m = 0; m < 4; ++m) {
        int j0 = m * 16 + hi * 4;
#pragma unroll
        for (int n = 0; n < 4; ++n) {
            int c = n * 16 + lrow;
            f32x4 v = accE[m][n];
            uint2 p; p.x = pack2(v[0], v[1]); p.y = pack2(v[2], v[3]);
            *(uint2*)(Sw + c * 128 + ((2 * j0) ^ ((c & 7) << 4))) = p;
        }
    }
    asm volatile("s_waitcnt lgkmcnt(0)" ::: "memory");

    // ---- inter-chunk scan: lane n (<32) owns complex mode n; pure-register chain
    if (lane < NH) {
        int n = lane;
        float ar = ltR[h * NH + n], ai = ltI[h * NH + n];
        unsigned ev[NCH];
#pragma unroll
        for (int c = 0; c < NCH; ++c)
            ev[c] = *(const unsigned*)(Sw + c * 128 + ((4 * n) ^ ((c & 7) << 4)));
        float sr = 0.f, si = 0.f;
#pragma unroll
        for (int c = 0; c < NCH; ++c) {
            *(unsigned*)(Sw + c * 128 + ((4 * n) ^ ((c & 7) << 4))) = pack2(sr, si);
            float er = bf2f((unsigned short)(ev[c] & 0xffffu));
            float ei = bf2f((unsigned short)(ev[c] >> 16));
            float nsr = fmaf(ar, sr, fmaf(-ai, si, er));
            float nsi = fmaf(ar, si, fmaf(ai, sr, ei));
            sr = nsr; si = nsi;
        }
    }
    asm volatile("s_waitcnt lgkmcnt(0)" ::: "memory");

    // ---- Y-GEMM: Y[t][c] = sum_k [M'|G][t][k] * { u[c][k] (k<64) ; S[c][k-64] }
    f32x4 acc[4][4];
#pragma unroll
    for (int m = 0; m < 4; ++m)
#pragma unroll
        for (int n = 0; n < 4; ++n) { f32x4 z = {0.f,0.f,0.f,0.f}; acc[m][n] = z; }
#pragma unroll
    for (int ks = 0; ks < 2; ++ks) {
        bf16x8 af[4];
#pragma unroll
        for (int m = 0; m < 4; ++m)
            af[m] = *(const bf16x8*)(Ap + (m * 16 + lrow) * KA + ks * 32 + lk8);
#pragma unroll
        for (int m = 0; m < 4; ++m)
#pragma unroll
            for (int n = 0; n < 4; ++n)
                acc[m][n] = __builtin_amdgcn_mfma_f32_16x16x32_bf16(af[m], ub[ks][n], acc[m][n], 0, 0, 0);
    }
#pragma unroll
    for (int ks = 2; ks < 4; ++ks) {
        bf16x8 af[4], bfr[4];
#pragma unroll
        for (int m = 0; m < 4; ++m)
            af[m] = *(const bf16x8*)(Ap + (m * 16 + lrow) * KA + ks * 32 + lk8);
#pragma unroll
        for (int n = 0; n < 4; ++n) {
            int c = n * 16 + lrow;
            int bo = (ks - 2) * 64 + lk8 * 2;
            bfr[n] = *(const bf16x8*)(Sw + c * 128 + (bo ^ ((c & 7) << 4)));
        }
#pragma unroll
        for (int m = 0; m < 4; ++m)
#pragma unroll
            for (int n = 0; n < 4; ++n)
                acc[m][n] = __builtin_amdgcn_mfma_f32_16x16x32_bf16(af[m], bfr[n], acc[m][n], 0, 0, 0);
    }
    // ---- epilogue: GELU (D already folded into M'), coalesced store yb[b][h][l]
    unsigned short* yrow = yb + ((size_t)b * HH + h) * LL;
#pragma unroll
    for (int m = 0; m < 4; ++m) {
        int t0 = m * 16 + hi * 4;
#pragma unroll
        for (int n = 0; n < 4; ++n) {
            int c = n * 16 + lrow;
            f32x4 v = acc[m][n];
            unsigned short o[4];
#pragma unroll
            for (int r = 0; r < 4; ++r) {
                float yo = v[r];
                float ge = 0.5f * yo * (1.0f + erff(yo * 0.70710678118f));
                o[r] = f2bf(ge);
            }
            uint2 pw;
            pw.x = (unsigned)o[0] | ((unsigned)o[1] << 16);
            pw.y = (unsigned)o[2] | ((unsigned)o[3] << 16);
            *(uint2*)(yrow + c * TCH + t0) = pw;
        }
    }
}

// ---------------- kT: transpose yb [b][h][l] -> yt [b*l][h] ----------------
__global__ __launch_bounds__(256) void kT_transpose(
    const unsigned short* __restrict__ yb, unsigned short* __restrict__ yt)
{
    __shared__ unsigned short T[64][130];        // stride 130 u16 -> 2-way max
    int bid = blockIdx.x;
    int lt = bid & 31;            // l-tile of 128
    int ht = (bid >> 5) & 7;      // h-tile of 64
    int b  = bid >> 8;
    int t = threadIdx.x;
#pragma unroll
    for (int r = 0; r < 4; ++r) {
        int chunk = r * 256 + t;                 // 1024 x 16B chunks
        int row = chunk >> 4;
        int c16 = chunk & 15;
        uint4 v = *(const uint4*)(yb + ((size_t)(b * HH + ht * 64 + row)) * LL
                                     + lt * 128 + c16 * 8);
        *(uint4*)&T[row][c16 * 8] = v;
    }
    __syncthreads();
    int oct = t & 7, lgrp = t >> 3;
    size_t obase = ((size_t)b * LL + (size_t)lt * 128) * HH + ht * 64 + oct * 8;
#pragma unroll
    for (int r = 0; r < 2; ++r) {
        int l = (r * 32 + lgrp) * 2;
        unsigned v[8];
#pragma unroll
        for (int k = 0; k < 8; ++k)
            v[k] = *(const unsigned*)&T[oct * 8 + k][l];
        uint4 w0, w1;
        w0.x = (v[0] & 0xffffu) | (v[1] << 16);
        w0.y = (v[2] & 0xffffu) | (v[3] << 16);
        w0.z = (v[4] & 0xffffu) | (v[5] << 16);
        w0.w = (v[6] & 0xffffu) | (v[7] << 16);
        w1.x = (v[0] >> 16) | (v[1] & 0xffff0000u);
        w1.y = (v[2] >> 16) | (v[3] & 0xffff0000u);
        w1.z = (v[4] >> 16) | (v[5] & 0xffff0000u);
        w1.w = (v[6] >> 16) | (v[7] & 0xffff0000u);
        *(uint4*)(yt + obase + (size_t)l * HH) = w0;
        *(uint4*)(yt + obase + (size_t)(l + 1) * HH) = w1;
    }
}

// ---------------- k4: GEMM z = Wp*y + bp, fused GLU (unchanged, known-good) ----------------
#define BM 128
#define BN 128
#define BKK 32

__global__ __launch_bounds__(256, 2) void k4_gemm(
    const unsigned short* __restrict__ Wp, const float* __restrict__ bp,
    const unsigned short* __restrict__ yt, float* __restrict__ out)
{
    __shared__ unsigned short As[BM * BKK];
    __shared__ unsigned short Bs[BN * BKK];
    int tid  = threadIdx.x;
    int bidx = blockIdx.x;
    int mtile = bidx & 7, ntile = bidx >> 3;
    int mbase = mtile * BM, nbase = ntile * BN;
    int lane = tid & 63;
    int wv = tid >> 6;
    int wr = wv >> 1, wc = wv & 1;
    int lrow = lane & 15;
    int lk = (lane >> 4) * 8;

    f32x4 acc[4][4];
#pragma unroll
    for (int m = 0; m < 4; ++m)
#pragma unroll
        for (int n = 0; n < 4; ++n) { f32x4 z = {0.f,0.f,0.f,0.f}; acc[m][n] = z; }

    for (int kk = 0; kk < HH; kk += BKK) {
#pragma unroll
        for (int p = 0; p < 2; ++p) {
            int chunk = p * 256 + tid;
            int row = chunk >> 2;
            int kc  = (chunk & 3) * 8;
            gload_lds16(Wp + (size_t)(mbase + row) * HH + kk + kc, &As[chunk * 8]);
            gload_lds16(yt + (size_t)(nbase + row) * HH + kk + kc, &Bs[chunk * 8]);
        }
        __syncthreads();
        bf16x8 af[4], bfr[4];
#pragma unroll
        for (int m = 0; m < 4; ++m)
            af[m] = *(const bf16x8*)&As[(wr * 64 + m * 16 + lrow) * BKK + lk];
#pragma unroll
        for (int nf = 0; nf < 4; ++nf)
            bfr[nf] = *(const bf16x8*)&Bs[(wc * 64 + nf * 16 + lrow) * BKK + lk];
#pragma unroll
        for (int m = 0; m < 4; ++m)
#pragma unroll
            for (int nf = 0; nf < 4; ++nf)
                acc[m][nf] = __builtin_amdgcn_mfma_f32_16x16x32_bf16(af[m], bfr[nf], acc[m][nf], 0, 0, 0);
        __syncthreads();
    }
#pragma unroll
    for (int m = 0; m < 4; ++m) {
        int go = mbase + wr * 64 + m * 16 + ((lane >> 4) * 4);
        float4 bv = *(const float4*)(bp + go);
#pragma unroll
        for (int nf = 0; nf < 4; ++nf) {
            int col  = nbase + wc * 64 + nf * 16 + lrow;
            int bcol = col >> 12;
            int lcol = col & (LL - 1);
            f32x4 v = acc[m][nf];
            float a0 = v[0] + bv.x, g0 = v[1] + bv.y;
            float a1 = v[2] + bv.z, g1 = v[3] + bv.w;
            float o0 = a0 / (1.0f + __expf(-g0));
            float o1 = a1 / (1.0f + __expf(-g1));
            size_t ob = ((size_t)bcol * HH + (size_t)(go >> 1)) * LL + lcol;
            out[ob] = o0;
            out[ob + LL] = o1;
        }
    }
}

extern "C" void kernel_launch(void* const* d_in, const int* in_sizes, int n_in,
                              void* d_out, int out_size, void* d_ws, size_t ws_size,
                              hipStream_t stream) {
    const float* u    = (const float*)d_in[0];
    const float* C    = (const float*)d_in[1];
    const float* ldt  = (const float*)d_in[2];
    const float* lar  = (const float*)d_in[3];
    const float* aim  = (const float*)d_in[4];
    const float* Dv   = (const float*)d_in[5];
    const float* W    = (const float*)d_in[6];
    const float* bias = (const float*)d_in[7];
    float* out = (float*)d_out;

    // ws layout (~79 MB)
    char* w = (char*)d_ws;
    float* c2R = (float*)w; w += (size_t)HH * NH * 4;
    float* c2I = (float*)w; w += (size_t)HH * NH * 4;
    float* ltR = (float*)w; w += (size_t)HH * NH * 4;
    float* ltI = (float*)w; w += (size_t)HH * NH * 4;
    float* xrA = (float*)w; w += (size_t)HH * NH * 4;
    float* xiA = (float*)w; w += (size_t)HH * NH * 4;
    float* bp  = (float*)w; w += (size_t)2 * HH * 4;
    unsigned short* Wp   = (unsigned short*)w; w += (size_t)2 * HH * HH * 2;
    unsigned short* Apan = (unsigned short*)w; w += (size_t)HH * TCH * KA * 2;   // 8MB
    unsigned short* Vpan = (unsigned short*)w; w += (size_t)HH * TCH * TCH * 2;  // 4MB
    unsigned short* yt   = (unsigned short*)w; w += (size_t)BB * LL * HH * 2;    // 64MB

    // yb (pre-transpose, 64MB bf16) lives in d_out (134MB): dead before k4,
    // kT consumes it before k4 overwrites out.
    unsigned short* yb = (unsigned short*)d_out;

    k0_params   <<<dim3(64),   dim3(256), 0, stream>>>(C, ldt, lar, aim, c2R, c2I, ltR, ltI, xrA, xiA);
    kw_pack     <<<dim3(256),  dim3(256), 0, stream>>>(W, bias, Wp, bp);
    kA_build    <<<dim3(512),  dim3(64),  0, stream>>>(c2R, c2I, xrA, xiA, Dv, Apan, Vpan);
    kBCD        <<<dim3(2048), dim3(256), 0, stream>>>(u, Apan, Vpan, ltR, ltI, yb);
    kT_transpose<<<dim3(4096), dim3(256), 0, stream>>>(yb, yt);
    k4_gemm     <<<dim3(4096), dim3(256), 0, stream>>>(Wp, bp, yt, out);
}